// Round 4
// baseline (349.811 us; speedup 1.0000x reference)
//
#include <hip/hip_runtime.h>

// ---------------------------------------------------------------------------
// SwitchMLP (top-1 MoE, SwiGLU) for MI355X / gfx950.  S=1024 B=4 DIM=768
// HID=2048 E=8, f32 in/out.
//
// All GEMM operands pre-staged in f16 MFMA fragment order; GEMM K-loops are
// pure global_load_dwordx4 -> v_mfma, no LDS, no barriers.
//   prep   : [blocks 0..1151] w1/w2/w3 f32 -> B-fragment cells, DIRECT global
//            gather (no LDS, no barrier);  [blocks 1152..2175] router (f64
//            logits, argmax -> eid, max-prob). counts zeroed by block 0.
//   lists  : 4096 threads: pos=atomicAdd(counts[eid]), lists[e][pos]=tok
//   gather : X rows -> Ag (A-fragment cells, zero-padded to 64-row tiles)
//   gemm1  : 64m x 128n, XCD-swizzled; silu(A@W1)*(A@W2) -> Hs (A-layout)
//   gemm2  : 32m x 128n, XCD-swizzled; out[tok] = bf16_rne(Hs@W3) * prob
//
// Fragment layouts (HW-validated rounds 1-3):
//   A-op: lane l holds A[m=l&15][k=(l>>4)*8+j]   (cell = 16m x 32k = 512 f16)
//   B-op: lane l holds B[k=(l>>4)*8+j][n=l&15]   (cell = 32k x 16n = 512 f16)
//   C/D : lane l holds C[row=(l>>4)*4+r][col=l&15]
// ---------------------------------------------------------------------------

#define T_TOK 4096
#define DIM   768
#define HID   2048
#define NE    8
#define ECAP  1024           // per-expert capacity (mean 512, sigma ~21)
#define KB1   24             // DIM/32  k-cells, gemm1
#define NB1   128            // HID/16  n-cells, w1/w2
#define KB2   64             // HID/32  k-cells, gemm2
#define NB2   48             // DIM/16  n-cells, w3
#define MBC   64             // ECAP/16 m-cells per expert
#define ESTRIDE 1572864      // DIM*HID == HID*DIM (per-expert element stride)

typedef _Float16 f16x8 __attribute__((ext_vector_type(8)));
typedef float    f32x4 __attribute__((ext_vector_type(4)));

__device__ __forceinline__ float bf16_rne(float v) {
    unsigned u = __float_as_uint(v);
    unsigned r = (u + 0x7fffu + ((u >> 16) & 1u)) & 0xffff0000u;
    return __uint_as_float(r);
}

// ---------------------------------------------------------------------------
// prep: convert (1152 blocks; wave = 16 cells in 4 chunks of 4 consecutive
// kb) + router (1024 blocks; wave = 1 token). No LDS anywhere.
__global__ __launch_bounds__(256) void moe_prep_kernel(
    const float* __restrict__ w1, const float* __restrict__ w2,
    const float* __restrict__ w3, const float* __restrict__ X,
    const float* __restrict__ rw, const float* __restrict__ rb,
    _Float16* __restrict__ w1s, _Float16* __restrict__ w2s,
    _Float16* __restrict__ w3s, int* __restrict__ eid,
    float* __restrict__ probs, int* __restrict__ counts)
{
    const int bid = blockIdx.x;
    const int t = threadIdx.x, w = t >> 6, l = t & 63;
    if (bid < 1152) {
        if (bid == 0 && t < NE) counts[t] = 0;
        const int mat = bid / 384;
        const float* src = (mat == 0) ? w1 : (mat == 1) ? w2 : w3;
        _Float16*    dst = (mat == 0) ? w1s : (mat == 1) ? w2s : w3s;
        const int N   = (mat == 2) ? DIM : HID;
        const int KBc = (mat == 2) ? KB2 : KB1;
        const int fq = l >> 4, fr = l & 15;
        const int cbase = (bid % 384) * 64 + w * 16;
#pragma unroll
        for (int ch = 0; ch < 4; ++ch) {
            const int cid = cbase + ch * 4;     // 4-aligned: never crosses nb
            const int e   = cid / 3072;
            const int r   = cid - e * 3072;
            const int nb  = r / KBc;
            const int kb0 = r - nb * KBc;
            const float* sp = src + (size_t)e * ESTRIDE
                            + (size_t)(fq * 8) * N + nb * 16 + fr;
            float v[4][8];
#pragma unroll
            for (int i = 0; i < 4; ++i)
#pragma unroll
                for (int j = 0; j < 8; ++j)
                    v[i][j] = sp[(size_t)((kb0 + i) * 32 + j) * N];
            _Float16* dp = dst + ((size_t)e * 3072 + (size_t)nb * KBc + kb0) * 512 + l * 8;
#pragma unroll
            for (int i = 0; i < 4; ++i) {
                f16x8 h;
#pragma unroll
                for (int j = 0; j < 8; ++j) h[j] = (_Float16)v[i][j];
                *(f16x8*)(dp + i * 512) = h;
            }
        }
    } else {
        const int tok = (bid - 1152) * 4 + w;
        const float4* X4 = (const float4*)(X + (size_t)tok * DIM);
        float4 xq[3];
#pragma unroll
        for (int jj = 0; jj < 3; ++jj) xq[jj] = X4[l + jj * 64];
        double lg[NE] = {0, 0, 0, 0, 0, 0, 0, 0};
#pragma unroll
        for (int jj = 0; jj < 3; ++jj)
#pragma unroll
            for (int q = 0; q < 4; ++q) {
                const int row = (l + jj * 64) * 4 + q;
                const double xv = (double)((const float*)&xq[jj])[q];
                const float4 w0 = *(const float4*)(rw + row * 8);
                const float4 w1v = *(const float4*)(rw + row * 8 + 4);
                lg[0] += xv * (double)w0.x;  lg[1] += xv * (double)w0.y;
                lg[2] += xv * (double)w0.z;  lg[3] += xv * (double)w0.w;
                lg[4] += xv * (double)w1v.x; lg[5] += xv * (double)w1v.y;
                lg[6] += xv * (double)w1v.z; lg[7] += xv * (double)w1v.w;
            }
#pragma unroll
        for (int e = 0; e < NE; ++e) {
#pragma unroll
            for (int off = 32; off >= 1; off >>= 1)
                lg[e] += __shfl_xor(lg[e], off, 64);
            lg[e] += (double)rb[e];
        }
        if (l == 0) {
            double m = lg[0]; int mi = 0;
#pragma unroll
            for (int e = 1; e < NE; ++e)
                if (lg[e] > m) { m = lg[e]; mi = e; }
            float sum = 0.f;
#pragma unroll
            for (int e = 0; e < NE; ++e) sum += expf((float)(lg[e] - m));
            probs[tok] = 1.0f / sum;
            eid[tok] = mi;
        }
    }
}

// ---------------------------------------------------------------------------
__global__ __launch_bounds__(256) void moe_lists_kernel(
    const int* __restrict__ eid, int* __restrict__ counts,
    int* __restrict__ lists)
{
    const int t = blockIdx.x * 256 + threadIdx.x;   // 0..4095
    const int e = eid[t];
    const int pos = atomicAdd(&counts[e], 1);
    if (pos < ECAP) lists[e * ECAP + pos] = t;
}

// ---------------------------------------------------------------------------
// Gather X rows per expert into A-fragment cells (f16), zero-padding rows
// beyond cnt up to the 64-row tile boundary.
__global__ __launch_bounds__(256) void moe_gather_kernel(
    const float* __restrict__ X, const int* __restrict__ lists,
    const int* __restrict__ counts, _Float16* __restrict__ Ag)
{
    const int e = blockIdx.z;
    int cnt = counts[e]; if (cnt > ECAP) cnt = ECAP;
    const int mgrp = blockIdx.y;
    if (mgrp * 64 >= ((cnt + 63) & ~63)) return;
    const int t = threadIdx.x, w = t >> 6, l = t & 63;
    const int mb = mgrp * 4 + w;
    const int m  = mb * 16 + (l & 15);
    const bool valid = (m < cnt);
    const int tok = valid ? lists[e * ECAP + m] : 0;
    const float* xr = X + (size_t)tok * DIM + (l >> 4) * 8;
#pragma unroll
    for (int i = 0; i < 4; ++i) {
        const int kb = blockIdx.x * 4 + i;
        float4 a = make_float4(0.f, 0.f, 0.f, 0.f), b = a;
        if (valid) {
            a = *(const float4*)(xr + kb * 32);
            b = *(const float4*)(xr + kb * 32 + 4);
        }
        f16x8 h;
        h[0] = (_Float16)a.x; h[1] = (_Float16)a.y; h[2] = (_Float16)a.z; h[3] = (_Float16)a.w;
        h[4] = (_Float16)b.x; h[5] = (_Float16)b.y; h[6] = (_Float16)b.z; h[7] = (_Float16)b.w;
        *(f16x8*)(Ag + ((size_t)(e * MBC + mb) * KB1 + kb) * 512 + l * 8) = h;
    }
}

// ---------------------------------------------------------------------------
// GEMM1: block = 64m x 128n (wave = 64m x 32n, both W1,W2). XCD swizzle:
// b = xcd + 8*(mb + 16*cgrp), c = cgrp*8+xcd = e*16+nb -> the 16 mb-blocks
// sharing one B-tile run consecutively on one XCD (B stays L2-resident).
__global__ __launch_bounds__(256) void moe_gemm1_kernel(
    const _Float16* __restrict__ Ag, const _Float16* __restrict__ w1s,
    const _Float16* __restrict__ w2s, const int* __restrict__ counts,
    _Float16* __restrict__ Hs)
{
    const int b = blockIdx.x;
    const int xcd = b & 7, slot = b >> 3;
    const int mb = slot & 15, cgrp = slot >> 4;
    const int c = cgrp * 8 + xcd;        // 0..127
    const int e = c >> 4, nb = c & 15;
    int cnt = counts[e]; if (cnt > ECAP) cnt = ECAP;
    if (mb * 64 >= cnt) return;
    const int t = threadIdx.x, w = t >> 6, l = t & 63;

    const _Float16* Ab = Ag + ((size_t)(e * MBC + mb * 4) * KB1) * 512 + l * 8;
    const int nc0 = e * NB1 + nb * 8 + w * 2;
    const _Float16* B1b = w1s + ((size_t)nc0 * KB1) * 512 + l * 8;
    const _Float16* B2b = w2s + ((size_t)nc0 * KB1) * 512 + l * 8;

    f32x4 acc1[4][2], acc2[4][2];
    const f32x4 zero = {0.f, 0.f, 0.f, 0.f};
#pragma unroll
    for (int i = 0; i < 4; ++i)
#pragma unroll
        for (int j = 0; j < 2; ++j) { acc1[i][j] = zero; acc2[i][j] = zero; }

#pragma unroll 2
    for (int kb = 0; kb < KB1; ++kb) {
        f16x8 a[4], p[2], q[2];
#pragma unroll
        for (int i = 0; i < 4; ++i)
            a[i] = *(const f16x8*)(Ab + ((size_t)(i * KB1 + kb)) * 512);
#pragma unroll
        for (int j = 0; j < 2; ++j) {
            p[j] = *(const f16x8*)(B1b + ((size_t)(j * KB1 + kb)) * 512);
            q[j] = *(const f16x8*)(B2b + ((size_t)(j * KB1 + kb)) * 512);
        }
#pragma unroll
        for (int i = 0; i < 4; ++i)
#pragma unroll
            for (int j = 0; j < 2; ++j) {
                acc1[i][j] = __builtin_amdgcn_mfma_f32_16x16x32_f16(a[i], p[j], acc1[i][j], 0, 0, 0);
                acc2[i][j] = __builtin_amdgcn_mfma_f32_16x16x32_f16(a[i], q[j], acc2[i][j], 0, 0, 0);
            }
    }

    // epilogue: silu(h1)*h2 -> f16; C-layout -> A-layout via per-wave LDS
    __shared__ _Float16 Ep[4][64 * 40];
    const int fq = l >> 4, fr = l & 15;
#pragma unroll
    for (int i = 0; i < 4; ++i)
#pragma unroll
        for (int j = 0; j < 2; ++j)
#pragma unroll
            for (int r = 0; r < 4; ++r) {
                const float h1 = acc1[i][j][r], h2 = acc2[i][j][r];
                const float s  = h1 / (1.f + __expf(-h1)) * h2;
                Ep[w][(i * 16 + fq * 4 + r) * 40 + j * 16 + fr] = (_Float16)s;
            }
    __syncthreads();
    const int kbH = nb * 4 + w;          // this wave's 32-wide hid cell
#pragma unroll
    for (int i = 0; i < 4; ++i) {
        f16x8 v = *(const f16x8*)&Ep[w][(i * 16 + fr) * 40 + fq * 8];
        *(f16x8*)(Hs + ((size_t)((e * MBC + mb * 4 + i) * KB2 + kbH)) * 512 + l * 8) = v;
    }
}

// ---------------------------------------------------------------------------
// GEMM2: block = 32m x 128n (wave = 32m x 32n), K=2048. XCD swizzle:
// b = xcd + 8*(mb + 32*cgrp), c = cgrp*8+xcd = e*6+nb (48 values).
// Epilogue: bf16_rne(acc) * prob, scatter f32 by token.
__global__ __launch_bounds__(256) void moe_gemm2_kernel(
    const _Float16* __restrict__ Hs, const _Float16* __restrict__ w3s,
    const int* __restrict__ lists, const int* __restrict__ counts,
    const float* __restrict__ probs, float* __restrict__ out)
{
    const int b = blockIdx.x;
    const int xcd = b & 7, slot = b >> 3;
    const int mb = slot & 31, cgrp = slot >> 5;   // cgrp 0..5
    const int c = cgrp * 8 + xcd;                 // 0..47
    const int e = c / 6, nb = c - e * 6;
    int cnt = counts[e]; if (cnt > ECAP) cnt = ECAP;
    if (mb * 32 >= cnt) return;
    const int t = threadIdx.x, w = t >> 6, l = t & 63;

    const _Float16* Ab = Hs + ((size_t)((e * MBC + mb * 2) * KB2)) * 512 + l * 8;
    const int nc0 = e * NB2 + nb * 8 + w * 2;
    const _Float16* Bb = w3s + ((size_t)nc0 * KB2) * 512 + l * 8;

    f32x4 acc[2][2];
    const f32x4 zero = {0.f, 0.f, 0.f, 0.f};
    acc[0][0] = zero; acc[0][1] = zero; acc[1][0] = zero; acc[1][1] = zero;

#pragma unroll 4
    for (int kb = 0; kb < KB2; ++kb) {
        f16x8 a[2], bf[2];
#pragma unroll
        for (int i = 0; i < 2; ++i)
            a[i] = *(const f16x8*)(Ab + ((size_t)(i * KB2 + kb)) * 512);
#pragma unroll
        for (int j = 0; j < 2; ++j)
            bf[j] = *(const f16x8*)(Bb + ((size_t)(j * KB2 + kb)) * 512);
#pragma unroll
        for (int i = 0; i < 2; ++i)
#pragma unroll
            for (int j = 0; j < 2; ++j)
                acc[i][j] = __builtin_amdgcn_mfma_f32_16x16x32_f16(a[i], bf[j], acc[i][j], 0, 0, 0);
    }

    const int* list = lists + e * ECAP;
    const int fq = l >> 4, fr = l & 15;
    const int c0 = nb * 128 + w * 32;
#pragma unroll
    for (int i = 0; i < 2; ++i)
#pragma unroll
        for (int r = 0; r < 4; ++r) {
            const int m = mb * 32 + i * 16 + fq * 4 + r;
            if (m < cnt) {
                const int tok = list[m];
                const float pb = probs[tok];
                float* orow = out + (size_t)tok * DIM + c0 + fr;
                orow[0]  = bf16_rne(acc[i][0][r]) * pb;
                orow[16] = bf16_rne(acc[i][1][r]) * pb;
            }
        }
}

// ---------------------------------------------------------------------------
extern "C" void kernel_launch(void* const* d_in, const int* in_sizes, int n_in,
                              void* d_out, int out_size, void* d_ws, size_t ws_size,
                              hipStream_t stream) {
    const float* X  = (const float*)d_in[0];
    const float* rw = (const float*)d_in[1];
    const float* rb = (const float*)d_in[2];
    const float* w1 = (const float*)d_in[3];
    const float* w2 = (const float*)d_in[4];
    const float* w3 = (const float*)d_in[5];
    float* out = (float*)d_out;

    // workspace layout (bytes); total ~121.7 MB
    char* ws = (char*)d_ws;
    int*      counts = (int*)(ws + 0);               //    256
    int*      eid    = (int*)(ws + 256);             //  16384
    float*    probs  = (float*)(ws + 16640);         //  16384
    int*      lists  = (int*)(ws + 33024);           //  32768 (8*ECAP*4)
    const size_t WSZ = 25165824;                     // 8*3072*512*2 each
    _Float16* w1s = (_Float16*)(ws + 65792);
    _Float16* w2s = (_Float16*)(ws + 65792 + WSZ);
    _Float16* w3s = (_Float16*)(ws + 65792 + 2 * WSZ);
    _Float16* Ag  = (_Float16*)(ws + 65792 + 3 * WSZ);              // 12.6 MB
    _Float16* Hs  = (_Float16*)(ws + 65792 + 3 * WSZ + 12582912);   // 33.6 MB

    hipLaunchKernelGGL(moe_prep_kernel, dim3(2176), dim3(256), 0, stream,
                       w1, w2, w3, X, rw, rb, w1s, w2s, w3s, eid, probs, counts);
    hipLaunchKernelGGL(moe_lists_kernel, dim3(16), dim3(256), 0, stream,
                       eid, counts, lists);
    hipLaunchKernelGGL(moe_gather_kernel, dim3(6, 16, 8), dim3(256), 0, stream,
                       X, lists, counts, Ag);
    hipLaunchKernelGGL(moe_gemm1_kernel, dim3(2048), dim3(256), 0, stream,
                       Ag, w1s, w2s, counts, Hs);
    hipLaunchKernelGGL(moe_gemm2_kernel, dim3(1536), dim3(256), 0, stream,
                       Hs, w3s, lists, counts, probs, out);
}